// Round 11
// baseline (222.670 us; speedup 1.0000x reference)
//
#include <hip/hip_runtime.h>

// Locally connected layer:
// out[b,o,h,w] = sum_{c,i,j} x[b,c,h+i,w+j] * W[o,c,h,w,i,j] + bias[o,h,w]
// x: [32,32,64,64] f32, W: [64,32,62,62,3,3] f32, bias: [64,62,62] f32
// out: [32,64,62,62] f32
//
// R11: explicit 8-phase pipeline with counted vmcnt (T4 idiom).
//  - W: coalesced gll->LDS (validated R10), now DEPTH-2 prefetch with 4
//    buffers; stage index min(c+2,31) keeps wait counts loop-invariant.
//  - x: 3-slot register rotation; phase bi: issue x(bi+2), wait vmcnt(6)
//    (x(bi) landed, x(bi+1..2)+gll stay in flight), 36 FMAs.
//  - gll W(c+2) issued at phase 6, AFTER all x loads (in-order vmcnt retire:
//    x-waits must never chain behind HBM W).
//  - DPP halo 0x101 (validated R8), chunked XCD swizzle (validated R3),
//    plain __launch_bounds__(256) (min-waves clause spills: R4/R8).

#define C_  32
#define B_  32
#define O_  64
#define H_  64
#define W_  64
#define OH_ 62
#define OW_ 62

typedef float vfloat2 __attribute__((ext_vector_type(2)));
typedef float vfloat4 __attribute__((ext_vector_type(4)));

#define GLL4(gaddr, laddr)                                                      \
    __builtin_amdgcn_global_load_lds(                                           \
        (const __attribute__((address_space(1))) void*)(gaddr),                 \
        (__attribute__((address_space(3))) void*)(laddr), 4, 0, 0)

// dst[lane] = src[lane+1] within each 16-lane row (validated R8)
__device__ __forceinline__ float dpp_nextlane(float v) {
    return __int_as_float(__builtin_amdgcn_update_dpp(
        0, __float_as_int(v), 0x101, 0xf, 0xf, true));
}

// counted wait + scheduling fence (N = outstanding VMEM ops allowed to remain)
#define WAITV(n) do {                                                           \
        asm volatile("s_waitcnt vmcnt(" #n ")" ::: "memory");                   \
        __builtin_amdgcn_sched_barrier(0);                                      \
    } while (0)

__global__ __launch_bounds__(256)
void lcl_kernel(const float* __restrict__ x,
                const float* __restrict__ Wt,
                const float* __restrict__ bias,
                float* __restrict__ out) {
    // per-wave private W row, 4 buffers (depth-2 prefetch): 4*4*2304 B = 36 KB
    __shared__ float ldsW[4][4][576];

    // ---- chunked XCD swizzle (hw: XCD = blockIdx.x % 8)
    const int nblk    = (O_ / 4) * OH_;              // 992 = 8 * 124
    const int i0      = blockIdx.x;
    const int logical = (i0 & 7) * (nblk >> 3) + (i0 >> 3);
    const int og      = logical & 15;                // o-group (fast)
    const int h       = logical >> 4;                // 0..61

    const int wv_i = threadIdx.x >> 6;               // wave 0..3
    const int o    = (og << 2) + wv_i;
    const int lane = threadIdx.x & 63;
    const int wg   = lane & 15;                      // w0 = 4*wg
    const int bg   = lane >> 4;                      // b0 = 8*bg
    const int w0   = wg * 4;
    const int b0   = bg * 8;
    const bool full = (wg < 15);                     // wg15 stores only w=60,61

    float acc[8][4];
#pragma unroll
    for (int bi = 0; bi < 8; ++bi)
#pragma unroll
        for (int wi = 0; wi < 4; ++wi) acc[bi][wi] = 0.f;

    // W row base (floats): o*C*34596 + h*558 (+ c*34596 per channel)
    const long wrowbase = (long)o * (C_ * 34596) + (long)h * 558;

    // x byte base for (b0, h, w0)
    const char* xb0 = (const char*)x + (unsigned)b0 * 524288u
                      + (unsigned)h * 256u + (unsigned)wg * 16u;

    // stage one 2232-B W row coalesced into this wave's LDS slot (9 gll dword;
    // tail instr covers [1976,2232), overlap [1976,2048) double-written same).
#define STAGE_W(buf, cidx) do {                                                 \
        const char* src_ = (const char*)(Wt + wrowbase + (long)(cidx) * 34596); \
        char* dst_ = (char*)&ldsW[buf][wv_i][0];                                \
        _Pragma("unroll")                                                       \
        for (int k_ = 0; k_ < 8; ++k_)                                          \
            GLL4(src_ + k_ * 256 + lane * 4, dst_ + k_ * 256);                  \
        GLL4(src_ + 1976 + lane * 4, dst_ + 1976);                              \
    } while (0)

    // lane reads its 36 W floats (9 x ds_read_b128, 144-B lane stride = 2-way
    // bank alias = free). wg=15 reads pad garbage, never stored.
#define DSREAD_W(buf) do {                                                      \
        const char* wrow_ = (const char*)&ldsW[buf][wv_i][0] + wg * 144;        \
        _Pragma("unroll")                                                       \
        for (int q_ = 0; q_ < 9; ++q_)                                          \
            wq[q_] = *reinterpret_cast<const vfloat4*>(wrow_ + q_ * 16);        \
    } while (0)

#define WQ(t) (wq[(t) >> 2][(t) & 3])

    // issue 3 float4 rows of batch b0+bi_ for channel cidx into slot s_
#define XLD(s_, cidx, bi_) do {                                                 \
        const char* p_ = xb0 + (unsigned)(bi_) * 524288u                        \
                         + (unsigned)(cidx) * 16384u;                           \
        xv##s_[0] = *reinterpret_cast<const float4*>(p_);                       \
        xv##s_[1] = *reinterpret_cast<const float4*>(p_ + 256);                 \
        xv##s_[2] = *reinterpret_cast<const float4*>(p_ + 512);                 \
    } while (0)

    // expand slot s_ via DPP halo and accumulate 36 FMAs into acc[bi_]
#define FMA1(s_, bi_) do {                                                      \
        float xr_[3][6];                                                        \
        _Pragma("unroll")                                                       \
        for (int r_ = 0; r_ < 3; ++r_) {                                        \
            xr_[r_][0] = xv##s_[r_].x; xr_[r_][1] = xv##s_[r_].y;               \
            xr_[r_][2] = xv##s_[r_].z; xr_[r_][3] = xv##s_[r_].w;               \
            xr_[r_][4] = dpp_nextlane(xv##s_[r_].x);                            \
            xr_[r_][5] = dpp_nextlane(xv##s_[r_].y);                            \
        }                                                                       \
        _Pragma("unroll")                                                       \
        for (int wi_ = 0; wi_ < 4; ++wi_)                                       \
        _Pragma("unroll")                                                       \
        for (int ii_ = 0; ii_ < 3; ++ii_)                                       \
        _Pragma("unroll")                                                       \
        for (int j_ = 0; j_ < 3; ++j_)                                          \
            acc[bi_][wi_] = fmaf(xr_[ii_][wi_ + j_],                            \
                                 WQ(wi_ * 9 + ii_ * 3 + j_),                    \
                                 acc[bi_][wi_]);                                \
    } while (0)

    vfloat4 wq[9];
    float4  xv0[3], xv1[3], xv2[3];

    // ---- prologue: depth-2 W prefetch; retire gll(0), keep gll(1) in flight
    STAGE_W(0, 0);
    STAGE_W(1, 1);
    WAITV(9);

    for (int c = 0; c < C_; ++c) {
        DSREAD_W(c & 3);                  // 9 ds_read_b128 (lgkm via compiler)
        XLD(0, c, 0);
        XLD(1, c, 1);
        // phases bi=0..5: issue x(bi+2) | wait x(bi) | FMA(bi)
        // outstanding at wait: [gll(c+1) only at bi0] + 3 x-triples -> vmcnt(6)
        XLD(2, c, 2); WAITV(6); FMA1(0, 0);
        XLD(0, c, 3); WAITV(6); FMA1(1, 1);
        XLD(1, c, 4); WAITV(6); FMA1(2, 2);
        XLD(2, c, 5); WAITV(6); FMA1(0, 3);
        XLD(0, c, 6); WAITV(6); FMA1(1, 4);
        XLD(1, c, 7); WAITV(6); FMA1(2, 5);
        // phase 6: stage W(c+2) (YOUNGEST; uniform min keeps counts literal)
        {
            const int cn = (c + 2 < C_) ? (c + 2) : (C_ - 1);
            STAGE_W((c + 2) & 3, cn);
        }
        WAITV(12); FMA1(0, 6);            // x6 done; x7(3)+gll(9) in flight
        WAITV(9);  FMA1(1, 7);            // x7 done; gll(c+2) stays in flight
    }

    // ---- epilogue: bias + nontemporal float2 stores (8B-aligned)
    const float* brow = bias + ((long)o * OH_ + h) * OW_ + w0;
    float2 bv0 = *reinterpret_cast<const float2*>(brow);
    float2 bv1;
    if (full) bv1 = *reinterpret_cast<const float2*>(brow + 2);
    else { bv1.x = 0.f; bv1.y = 0.f; }

#pragma unroll
    for (int bi = 0; bi < 8; ++bi) {
        float* orow = out + (((long)(b0 + bi) * O_ + o) * OH_ + h) * OW_ + w0;
        vfloat2 s0; s0.x = acc[bi][0] + bv0.x; s0.y = acc[bi][1] + bv0.y;
        __builtin_nontemporal_store(s0, reinterpret_cast<vfloat2*>(orow));
        if (full) {
            vfloat2 s1; s1.x = acc[bi][2] + bv1.x; s1.y = acc[bi][3] + bv1.y;
            __builtin_nontemporal_store(s1, reinterpret_cast<vfloat2*>(orow) + 1);
        }
    }

#undef STAGE_W
#undef DSREAD_W
#undef WQ
#undef XLD
#undef FMA1
}

extern "C" void kernel_launch(void* const* d_in, const int* in_sizes, int n_in,
                              void* d_out, int out_size, void* d_ws, size_t ws_size,
                              hipStream_t stream) {
    const float* x    = (const float*)d_in[0];
    const float* Wt   = (const float*)d_in[1];
    const float* bias = (const float*)d_in[2];
    float* out        = (float*)d_out;

    dim3 grid((O_ / 4) * OH_);   // 992 blocks, XCD-swizzled in-kernel
    dim3 block(256);
    lcl_kernel<<<grid, block, 0, stream>>>(x, Wt, bias, out);
}

// Round 12
// 177.030 us; speedup vs baseline: 1.2578x; 1.2578x over previous
//
#include <hip/hip_runtime.h>

// Locally connected layer:
// out[b,o,h,w] = sum_{c,i,j} x[b,c,h+i,w+j] * W[o,c,h,w,i,j] + bias[o,h,w]
// x: [32,32,64,64] f32, W: [64,32,62,62,3,3] f32, bias: [64,62,62] f32
// out: [32,64,62,62] f32
//
// R12: TLP + FIFO-clean W pipeline.
//  - 1 wave per block (64 threads, 3968 blocks): kernel is barrier-free, so
//    block granularity was pure overhead. LDS 9.2 KB/block, VGPR ~116 ->
//    ~16 waves/CU (was 8). Waves self-stagger; latency hidden by TLP.
//  - W: coalesced gll->LDS (validated R10), depth-2 prefetch, 4 buffers.
//    Per channel: DSREAD_W(c) | 24 x float4 | gll W(c+2) (YOUNGEST) | FMAs.
//    x-waits (compiler-counted) retire gll(c+1) first (FIFO) - but that gll
//    is a full channel old (~>1000 cy of cover). Top wait = vmcnt(9): gll(c)
//    landed, gll(c+1) stays in flight. NEVER vmcnt(0) (R10's stall), NEVER
//    waits that drain a just-issued gll (R11's mistake).
//  - DPP halo 0x101 (validated R8), chunked XCD swizzle (validated R3),
//    plain launch_bounds (min-waves clause spills: R4/R8).

#define C_  32
#define B_  32
#define O_  64
#define H_  64
#define W_  64
#define OH_ 62
#define OW_ 62

typedef float vfloat2 __attribute__((ext_vector_type(2)));
typedef float vfloat4 __attribute__((ext_vector_type(4)));

#define GLL4(gaddr, laddr)                                                      \
    __builtin_amdgcn_global_load_lds(                                           \
        (const __attribute__((address_space(1))) void*)(gaddr),                 \
        (__attribute__((address_space(3))) void*)(laddr), 4, 0, 0)

// dst[lane] = src[lane+1] within each 16-lane row (validated R8)
__device__ __forceinline__ float dpp_nextlane(float v) {
    return __int_as_float(__builtin_amdgcn_update_dpp(
        0, __float_as_int(v), 0x101, 0xf, 0xf, true));
}

#define WAITV(n) do {                                                           \
        asm volatile("s_waitcnt vmcnt(" #n ")" ::: "memory");                   \
        __builtin_amdgcn_sched_barrier(0);                                      \
    } while (0)

__global__ __launch_bounds__(64)
void lcl_kernel(const float* __restrict__ x,
                const float* __restrict__ Wt,
                const float* __restrict__ bias,
                float* __restrict__ out) {
    // this wave's private W row, 4 buffers (depth-2 prefetch): 9216 B
    __shared__ float ldsW[4][576];

    // ---- chunked XCD swizzle (hw: XCD = blockIdx.x % 8)
    const int nblk    = O_ * OH_;                    // 3968 = 8 * 496
    const int i0      = blockIdx.x;
    const int logical = (i0 & 7) * (nblk >> 3) + (i0 >> 3);
    const int o       = logical & 63;                // o fast -> same-h neighbors
    const int h       = logical >> 6;                // 0..61

    const int lane = threadIdx.x;                    // 0..63
    const int wg   = lane & 15;                      // w0 = 4*wg
    const int bg   = lane >> 4;                      // b0 = 8*bg
    const int w0   = wg * 4;
    const int b0   = bg * 8;
    const bool full = (wg < 15);                     // wg15 stores only w=60,61

    float acc[8][4];
#pragma unroll
    for (int bi = 0; bi < 8; ++bi)
#pragma unroll
        for (int wi = 0; wi < 4; ++wi) acc[bi][wi] = 0.f;

    // W row base (floats): o*C*34596 + h*558 (+ c*34596 per channel)
    const long wrowbase = (long)o * (C_ * 34596) + (long)h * 558;

    // x byte base for (b0, h, w0)
    const char* xb0 = (const char*)x + (unsigned)b0 * 524288u
                      + (unsigned)h * 256u + (unsigned)wg * 16u;

    // stage one 2232-B W row coalesced into LDS (9 gll dword; tail instr
    // covers [1976,2232), overlap [1976,2048) double-written with same data).
#define STAGE_W(buf, cidx) do {                                                 \
        const char* src_ = (const char*)(Wt + wrowbase + (long)(cidx) * 34596); \
        char* dst_ = (char*)&ldsW[buf][0];                                      \
        _Pragma("unroll")                                                       \
        for (int k_ = 0; k_ < 8; ++k_)                                          \
            GLL4(src_ + k_ * 256 + lane * 4, dst_ + k_ * 256);                  \
        GLL4(src_ + 1976 + lane * 4, dst_ + 1976);                              \
    } while (0)

    // lane reads its 36 W floats (9 x ds_read_b128, 144-B lane stride = 2-way
    // bank alias = free per m136). wg=15 reads pad garbage, never stored.
#define DSREAD_W(buf) do {                                                      \
        const char* wrow_ = (const char*)&ldsW[buf][0] + wg * 144;              \
        _Pragma("unroll")                                                       \
        for (int q_ = 0; q_ < 9; ++q_)                                          \
            wq[q_] = *reinterpret_cast<const vfloat4*>(wrow_ + q_ * 16);        \
    } while (0)

#define WQ(t) (wq[(t) >> 2][(t) & 3])

#define XLOADALL(cidx) do {                                                     \
        _Pragma("unroll")                                                       \
        for (int bi_ = 0; bi_ < 8; ++bi_) {                                     \
            const char* p_ = xb0 + (unsigned)bi_ * 524288u                      \
                             + (unsigned)(cidx) * 16384u;                       \
            xv[bi_][0] = *reinterpret_cast<const float4*>(p_);                  \
            xv[bi_][1] = *reinterpret_cast<const float4*>(p_ + 256);            \
            xv[bi_][2] = *reinterpret_cast<const float4*>(p_ + 512);            \
        }                                                                       \
    } while (0)

#define FMAALL() do {                                                           \
        _Pragma("unroll")                                                       \
        for (int bi_ = 0; bi_ < 8; ++bi_) {                                     \
            float xr_[3][6];                                                    \
            _Pragma("unroll")                                                   \
            for (int r_ = 0; r_ < 3; ++r_) {                                    \
                xr_[r_][0] = xv[bi_][r_].x; xr_[r_][1] = xv[bi_][r_].y;         \
                xr_[r_][2] = xv[bi_][r_].z; xr_[r_][3] = xv[bi_][r_].w;         \
                xr_[r_][4] = dpp_nextlane(xv[bi_][r_].x);                       \
                xr_[r_][5] = dpp_nextlane(xv[bi_][r_].y);                       \
            }                                                                   \
            _Pragma("unroll")                                                   \
            for (int wi_ = 0; wi_ < 4; ++wi_)                                   \
            _Pragma("unroll")                                                   \
            for (int ii_ = 0; ii_ < 3; ++ii_)                                   \
            _Pragma("unroll")                                                   \
            for (int j_ = 0; j_ < 3; ++j_)                                      \
                acc[bi_][wi_] = fmaf(xr_[ii_][wi_ + j_],                        \
                                     WQ(wi_ * 9 + ii_ * 3 + j_),                \
                                     acc[bi_][wi_]);                            \
        }                                                                       \
    } while (0)

    vfloat4 wq[9];
    float4  xv[8][3];

    // ---- prologue: depth-2 W prefetch
    STAGE_W(0, 0);
    STAGE_W(1, 1);

    for (int c = 0; c < C_; ++c) {
        // gll(c) landed iff <= 9 outstanding (only gll(c+1) may remain).
        WAITV(9);
        DSREAD_W(c & 3);                  // 9 ds_read_b128
        XLOADALL(c);                      // 24 x float4 (oldest VMEM of c)
        __builtin_amdgcn_sched_barrier(0);
        {                                 // gll W(c+2): YOUNGEST, in flight
            const int cn = (c + 2 < C_) ? (c + 2) : (C_ - 1);
            STAGE_W((c + 2) & 3, cn);
        }
        __builtin_amdgcn_sched_barrier(0);
        FMAALL();                         // compiler-counted x waits; gll rides
    }

    // ---- epilogue: bias + nontemporal float2 stores (8B-aligned)
    const float* brow = bias + ((long)o * OH_ + h) * OW_ + w0;
    float2 bv0 = *reinterpret_cast<const float2*>(brow);
    float2 bv1;
    if (full) bv1 = *reinterpret_cast<const float2*>(brow + 2);
    else { bv1.x = 0.f; bv1.y = 0.f; }

#pragma unroll
    for (int bi = 0; bi < 8; ++bi) {
        float* orow = out + (((long)(b0 + bi) * O_ + o) * OH_ + h) * OW_ + w0;
        vfloat2 s0; s0.x = acc[bi][0] + bv0.x; s0.y = acc[bi][1] + bv0.y;
        __builtin_nontemporal_store(s0, reinterpret_cast<vfloat2*>(orow));
        if (full) {
            vfloat2 s1; s1.x = acc[bi][2] + bv1.x; s1.y = acc[bi][3] + bv1.y;
            __builtin_nontemporal_store(s1, reinterpret_cast<vfloat2*>(orow) + 1);
        }
    }

#undef STAGE_W
#undef DSREAD_W
#undef WQ
#undef XLOADALL
#undef FMAALL
}

extern "C" void kernel_launch(void* const* d_in, const int* in_sizes, int n_in,
                              void* d_out, int out_size, void* d_ws, size_t ws_size,
                              hipStream_t stream) {
    const float* x    = (const float*)d_in[0];
    const float* Wt   = (const float*)d_in[1];
    const float* bias = (const float*)d_in[2];
    float* out        = (float*)d_out;

    dim3 grid(O_ * OH_);   // 3968 one-wave blocks, XCD-swizzled in-kernel
    dim3 block(64);
    lcl_kernel<<<grid, block, 0, stream>>>(x, Wt, bias, out);
}